// Round 10
// baseline (362.511 us; speedup 1.0000x reference)
//
#include <hip/hip_runtime.h>

#define NPTS 16384
#define KNN 16
#define HID 64
#define NCLS 10

#define QPB 8      // queries per block (knn kernel)
#define QPW 2      // queries per wave
#define SCAP 128   // per-query survivor capacity (LDS list)

// distance helper: identical fmaf chain everywhere so τ comparisons are
// bit-exact across phases (drop sq_i: rank-invariant per query)
__device__ __forceinline__ float distf(float4 q, float4 p) {
    float dot = fmaf(q.x, p.x, fmaf(q.y, p.y, q.z * p.z));
    return fmaf(-2.f, dot, p.w);
}

// monotone float->u32, packed with index: ascending u64 order == (d asc, j asc)
__device__ __forceinline__ unsigned long long dkey(float v, int j) {
    unsigned u = __float_as_uint(v);
    u = (u & 0x80000000u) ? ~u : (u | 0x80000000u);
    return ((unsigned long long)u << 32) | (unsigned)j;
}

__device__ __forceinline__ unsigned long long shfl_xor_u64(unsigned long long x, int m) {
    unsigned hi = (unsigned)__shfl_xor((int)(x >> 32), m, 64);
    unsigned lo = (unsigned)__shfl_xor((int)(x & 0xffffffffu), m, 64);
    return ((unsigned long long)hi << 32) | lo;
}

// exact wave-wide top-16 (overflow slow path only)
__device__ __forceinline__ void wave_top16_16(unsigned long long (&key)[16], int lane,
                                              int q, int* __restrict__ idx) {
    int outj = 0x7fffffff;
    for (int r = 0; r < 16; ++r) {
        unsigned long long gm = key[0];
#pragma unroll
        for (int s = 1; s < 16; ++s) gm = key[s] < gm ? key[s] : gm;
#pragma unroll
        for (int st = 1; st < 64; st <<= 1) {
            unsigned long long o = shfl_xor_u64(gm, st);
            gm = o < gm ? o : gm;
        }
        if (lane == r) outj = (int)(gm & 0xffffffffu);
#pragma unroll
        for (int s = 0; s < 16; ++s)
            if (key[s] == gm) key[s] = ~0ull;
    }
    if (lane < 16) idx[q * KNN + lane] = outj;
}

// pos (N,3) -> pos4 (x,y,z,|p|^2)
__global__ void prep_kernel(const float* __restrict__ pos, float4* __restrict__ pos4) {
    int i = blockIdx.x * 256 + threadIdx.x;
    if (i < NPTS) {
        float x = pos[3 * i], y = pos[3 * i + 1], z = pos[3 * i + 2];
        pos4[i] = make_float4(x, y, z, fmaf(x, x, fmaf(y, y, z * z)));
    }
}

// ONE-KERNEL kNN. Block = 4 waves x 2 queries/wave. Grid 2048 -> 8 blocks/CU
// (100% wave occupancy cap).
// Phase A: branchless per-lane min scan -> in-wave tau (16 streams = lane mod 16;
//   tau = max of stream minima >= d16 since stream argmins are distinct).
// Phase B: tau-filtered push of (d,j) keys into wave-private LDS lists.
// Extraction: LDS rank-select (ranks 0..15 unique under (d,j) tie-break).
__global__ __launch_bounds__(256) void knn_kernel(const float4* __restrict__ pos4,
                                                  int* __restrict__ idx) {
    __shared__ float4 tile[256];
    __shared__ unsigned long long keys[QPB][SCAP];   // 8KB
    __shared__ int knt[QPB];
    int tid = threadIdx.x;
    int lane = tid & 63;
    int w = tid >> 6;
    int qb = blockIdx.x * QPB + w * QPW;
    float4 q0 = pos4[qb + 0], q1 = pos4[qb + 1];

    // ---- Phase A: per-lane minima (branchless) ----
    float m0 = INFINITY, m1 = INFINITY;
    for (int tb = 0; tb < NPTS; tb += 256) {
        __syncthreads();
        tile[tid] = pos4[tb + tid];
        __syncthreads();
#pragma unroll
        for (int r = 0; r < 4; ++r) {
            float4 p = tile[r * 64 + lane];
            m0 = fminf(m0, distf(q0, p));
            m1 = fminf(m1, distf(q1, p));
        }
    }
    // stream minima: min over lanes {l, l^16, l^32, l^48} (stream = lane mod 16)
    m0 = fminf(m0, __shfl_xor(m0, 16, 64));
    m1 = fminf(m1, __shfl_xor(m1, 16, 64));
    m0 = fminf(m0, __shfl_xor(m0, 32, 64));
    m1 = fminf(m1, __shfl_xor(m1, 32, 64));
    // tau = max over the 16 stream minima
#pragma unroll
    for (int mk = 1; mk <= 8; mk <<= 1) {
        m0 = fmaxf(m0, __shfl_xor(m0, mk, 64));
        m1 = fmaxf(m1, __shfl_xor(m1, mk, 64));
    }
    float tq0 = m0, tq1 = m1;
    if (lane < QPW) knt[w * QPW + lane] = 0;   // wave-private; same-wave LDS order

    // ---- Phase B: tau-filtered key push ----
    for (int tb = 0; tb < NPTS; tb += 256) {
        __syncthreads();
        tile[tid] = pos4[tb + tid];
        __syncthreads();
#pragma unroll
        for (int r = 0; r < 4; ++r) {
            int jj = r * 64 + lane;
            float4 p = tile[jj];
            int j = tb + jj;
            float v0 = distf(q0, p);
            float v1 = distf(q1, p);
            if (v0 <= tq0) { int s = atomicAdd(&knt[w * QPW + 0], 1); if (s < SCAP) keys[w * QPW + 0][s] = dkey(v0, j); }
            if (v1 <= tq1) { int s = atomicAdd(&knt[w * QPW + 1], 1); if (s < SCAP) keys[w * QPW + 1][s] = dkey(v1, j); }
        }
    }

    // ---- Extraction: wave-private rank-select, no barriers ----
#pragma unroll
    for (int qi = 0; qi < QPW; ++qi) {
        int q = qb + qi;
        int ntot = knt[w * QPW + qi];
        if (ntot <= SCAP) {
            unsigned long long k0 = (lane < ntot) ? keys[w * QPW + qi][lane] : ~0ull;
            unsigned long long k1 = (lane + 64 < ntot) ? keys[w * QPW + qi][lane + 64] : ~0ull;
            int r0 = 0, r1 = 0;
            for (int t = 0; t < ntot; ++t) {
                unsigned long long k = keys[w * QPW + qi][t];   // broadcast ds_read
                r0 += (int)(k < k0);
                r1 += (int)(k < k1);
            }
            if (lane < ntot && r0 < KNN) idx[q * KNN + r0] = (int)(k0 & 0xffffffffu);
            if (lane + 64 < ntot && r1 < KNN) idx[q * KNN + r1] = (int)(k1 & 0xffffffffu);
        } else {
            // overflow (astronomically rare): exact wave-cooperative rescan
            float tq = (qi == 0) ? tq0 : tq1;
            float4 qq = pos4[q];
            unsigned long long key[16];
#pragma unroll
            for (int u = 0; u < 16; ++u) key[u] = ~0ull;
            for (int j = lane; j < NPTS; j += 64) {
                float v = distf(qq, pos4[j]);
                unsigned long long k = dkey(v, j);
                if (v <= tq && k < key[15]) {
#pragma unroll
                    for (int s = 0; s < 16; ++s) {
                        unsigned long long mn = k < key[s] ? k : key[s];
                        unsigned long long mx = k < key[s] ? key[s] : k;
                        key[s] = mn;
                        k = mx;
                    }
                }
            }
            wave_top16_16(key, lane, q, idx);
        }
    }
}

// EdgeConv factorization: m[k][t] = C[i][t] + Y[j][t]; max commutes with +C.

// ec1_pre: C1[p][t] = b1 + x·(W1a-W1b) ; Y1[p][t] = x·W1b
__global__ __launch_bounds__(256) void ec1_pre_kernel(const float4* __restrict__ pos4,
                                                      const float* __restrict__ W1,
                                                      const float* __restrict__ b1,
                                                      float* __restrict__ C1,
                                                      float* __restrict__ Y1) {
    int t = threadIdx.x & 63;
    int p = blockIdx.x * 4 + (threadIdx.x >> 6);
    float4 x = pos4[p];
    float w0 = W1[0 * HID + t], w1 = W1[1 * HID + t], w2 = W1[2 * HID + t];
    float v0 = W1[3 * HID + t], v1 = W1[4 * HID + t], v2 = W1[5 * HID + t];
    float y = fmaf(x.x, v0, fmaf(x.y, v1, x.z * v2));
    float cc = b1[t] + x.x * (w0 - v0) + x.y * (w1 - v1) + x.z * (w2 - v2);
    Y1[p * HID + t] = y;
    C1[p * HID + t] = cc;
}

// ec1_max: h1[p][t] = relu(C1[p][t] + max_k Y1[idx[p][k]][t])
__global__ __launch_bounds__(256) void ec1_max_kernel(const float* __restrict__ C1,
                                                      const float* __restrict__ Y1,
                                                      const int* __restrict__ idx,
                                                      float* __restrict__ h1) {
    int t = threadIdx.x & 63;
    int p = blockIdx.x * 4 + (threadIdx.x >> 6);
    float m = -INFINITY;
#pragma unroll
    for (int k = 0; k < KNN; ++k) {
        int j = idx[p * KNN + k];
        m = fmaxf(m, Y1[j * HID + t]);
    }
    h1[p * HID + t] = fmaxf(C1[p * HID + t] + m, 0.f);
}

// ec2_pre: C2[p][t] = b2 + h1[p]·(W2a-W2b) ; Y2[p][t] = h1[p]·W2b
__global__ __launch_bounds__(256) void ec2_pre_kernel(const float* __restrict__ h1,
                                                      const float* __restrict__ W2,
                                                      const float* __restrict__ b2,
                                                      float* __restrict__ C2,
                                                      float* __restrict__ Y2) {
    int t = threadIdx.x & 63;
    int r = threadIdx.x >> 6;            // 0..3
    int pb = blockIdx.x * 16 + r * 4;
    float aa[4] = {0.f, 0.f, 0.f, 0.f};
    float ab[4] = {0.f, 0.f, 0.f, 0.f};
#pragma unroll 8
    for (int f = 0; f < 64; ++f) {
        float wa = W2[f * HID + t];
        float wb = W2[(64 + f) * HID + t];
#pragma unroll
        for (int i = 0; i < 4; ++i) {
            float h = h1[(pb + i) * HID + f];   // wave-uniform broadcast
            aa[i] = fmaf(h, wa, aa[i]);
            ab[i] = fmaf(h, wb, ab[i]);
        }
    }
    float bt = b2[t];
#pragma unroll
    for (int i = 0; i < 4; ++i) {
        C2[(pb + i) * HID + t] = bt + aa[i] - ab[i];
        Y2[(pb + i) * HID + t] = ab[i];
    }
}

// ec2_maxpool: val = relu(C2 + max_k Y2[idx[k]]); block-partial max-pool.
__global__ __launch_bounds__(256) void ec2_maxpool_kernel(const float* __restrict__ C2,
                                                          const float* __restrict__ Y2,
                                                          const int* __restrict__ idx,
                                                          float* __restrict__ gpartial) {
    int t = threadIdx.x & 63;
    int lp = threadIdx.x >> 6;
    int p = blockIdx.x * 4 + lp;
    float m = -INFINITY;
#pragma unroll
    for (int k = 0; k < KNN; ++k) {
        int j = idx[p * KNN + k];
        m = fmaxf(m, Y2[j * HID + t]);
    }
    float val = fmaxf(C2[p * HID + t] + m, 0.f);
    __shared__ float red[4][64];
    red[lp][t] = val;
    __syncthreads();
    if (lp == 0) {
        float g = fmaxf(fmaxf(red[0][t], red[1][t]), fmaxf(red[2][t], red[3][t]));
        gpartial[blockIdx.x * 64 + t] = g;
    }
}

// greduce2: 4096 -> 256 partial rows, fully coalesced, 256 parallel blocks.
__global__ __launch_bounds__(256) void greduce2_kernel(const float* __restrict__ gpartial,
                                                       float* __restrict__ gp2) {
    __shared__ float red[4][64];
    int f = threadIdx.x & 63;
    int w = threadIdx.x >> 6;
    int r0 = blockIdx.x * 16 + w * 4;
    float m = -INFINITY;
#pragma unroll
    for (int r = 0; r < 4; ++r) m = fmaxf(m, gpartial[(r0 + r) * 64 + f]);
    red[w][f] = m;
    __syncthreads();
    if (w == 0)
        gp2[blockIdx.x * 64 + f] =
            fmaxf(fmaxf(red[0][f], red[1][f]), fmaxf(red[2][f], red[3][f]));
}

// tail2: 256 rows -> g[64], then linear head. One block (cheap now).
__global__ __launch_bounds__(256) void tail2_kernel(const float* __restrict__ gp2,
                                                    const float* __restrict__ Wc,
                                                    const float* __restrict__ bc,
                                                    float* __restrict__ out) {
    __shared__ float red[4][64];
    __shared__ float g[64];
    int f = threadIdx.x & 63;
    int w = threadIdx.x >> 6;
    float m = -INFINITY;
    for (int i = w; i < 256; i += 4) m = fmaxf(m, gp2[i * 64 + f]);
    red[w][f] = m;
    __syncthreads();
    if (w == 0) g[f] = fmaxf(fmaxf(red[0][f], red[1][f]), fmaxf(red[2][f], red[3][f]));
    __syncthreads();
    if (threadIdx.x < NCLS) {
        float a = bc[threadIdx.x];
#pragma unroll
        for (int h = 0; h < HID; ++h) a = fmaf(g[h], Wc[h * NCLS + threadIdx.x], a);
        out[threadIdx.x] = a;
    }
}

extern "C" void kernel_launch(void* const* d_in, const int* in_sizes, int n_in,
                              void* d_out, int out_size, void* d_ws, size_t ws_size,
                              hipStream_t stream) {
    const float* pos = (const float*)d_in[0];
    // d_in[1] = batch (all zeros, num_segments=1) -> unused
    const float* W1 = (const float*)d_in[2];
    const float* b1 = (const float*)d_in[3];
    const float* W2 = (const float*)d_in[4];
    const float* b2 = (const float*)d_in[5];
    const float* Wc = (const float*)d_in[6];
    const float* bc = (const float*)d_in[7];
    float* out = (float*)d_out;

    char* ws = (char*)d_ws;
    size_t o = 0;
    auto alloc = [&](size_t bytes) { size_t r = o; o += (bytes + 255) & ~size_t(255); return r; };
    size_t fm = (size_t)NPTS * HID * 4;
    size_t o_pos4 = alloc((size_t)NPTS * 16);
    size_t o_idx = alloc((size_t)NPTS * KNN * 4);
    size_t o_h1 = alloc(fm);
    size_t o_C1 = alloc(fm);
    size_t o_Y1 = alloc(fm);
    size_t o_C2 = alloc(fm);
    size_t o_Y2 = alloc(fm);
    size_t o_gp = alloc((size_t)(NPTS / 4) * HID * 4);
    size_t o_gp2 = alloc((size_t)256 * HID * 4);

    float4* pos4 = (float4*)(ws + o_pos4);
    int* idx = (int*)(ws + o_idx);
    float* h1 = (float*)(ws + o_h1);
    float* C1 = (float*)(ws + o_C1);
    float* Y1 = (float*)(ws + o_Y1);
    float* C2 = (float*)(ws + o_C2);
    float* Y2 = (float*)(ws + o_Y2);
    float* gp = (float*)(ws + o_gp);
    float* gp2 = (float*)(ws + o_gp2);

    prep_kernel<<<NPTS / 256, 256, 0, stream>>>(pos, pos4);
    knn_kernel<<<NPTS / QPB, 256, 0, stream>>>(pos4, idx);
    ec1_pre_kernel<<<NPTS / 4, 256, 0, stream>>>(pos4, W1, b1, C1, Y1);
    ec1_max_kernel<<<NPTS / 4, 256, 0, stream>>>(C1, Y1, idx, h1);
    ec2_pre_kernel<<<NPTS / 16, 256, 0, stream>>>(h1, W2, b2, C2, Y2);
    ec2_maxpool_kernel<<<NPTS / 4, 256, 0, stream>>>(C2, Y2, idx, gp);
    greduce2_kernel<<<256, 256, 0, stream>>>(gp, gp2);
    tail2_kernel<<<1, 256, 0, stream>>>(gp2, Wc, bc, out);
}